// Round 13
// baseline (32.157 us; speedup 1.0000x reference)
//
#include <hip/hip_runtime.h>
#include <math.h>

// Problem constants (fixed by setup_inputs)
#define B 64
#define T 60
#define NA 3
#define NS 3
#define BT (B*T)

#define NB_SCAN 2048
#define NB_CORR ((BT + 255) / 256)    // 15
#define NB_ALL (NB_SCAN + NB_CORR)    // 2063 (corr blocks MUST be last: they
                                      // are the 15 non-resident overflow blocks)
#define NT 524288                     // scan threads; NT % 5 == 3
#define N_TOTAL 6451200.0f

// Flattened det space: 8064000 float4s. Chunk = 256 float4s.
// Tensor boundaries at chunk 24000 (det0/det1) and 30000 (det1/det2) are
// block-uniform because chunk(b,k) = b + 2048*k.
#define CH_B1 24000u
#define CH_B2 30000u
#define OFF_D1 6144000
#define OFF_D2 7680000
#define NB_16TH 780                   // blocks doing the 16th load (all det2)

typedef float float4n __attribute__((ext_vector_type(4)));

__device__ __forceinline__ float softplus_f(float x) {
    // stable softplus with fast hw transcendentals; abs err < 1e-6
    float e = __expf(-fabsf(x));
    return fmaxf(x, 0.0f) + __logf(1.0f + e);
}

__device__ __forceinline__ float pickn(float4n f, int ph) {
    // ph in 1..4 -> component ph-1 (caller gates ph==0)
    return (ph == 1) ? f[0] : (ph == 2) ? f[1] : (ph == 3) ? f[2] : f[3];
}

__device__ __forceinline__ float block_reduce_sum(float v) {
    __syncthreads();
    for (int o = 32; o > 0; o >>= 1) v += __shfl_down(v, o, 64);
    __shared__ float s[4];
    int lane = threadIdx.x & 63;
    int w = threadIdx.x >> 6;
    if (lane == 0) s[w] = v;
    __syncthreads();
    if (threadIdx.x == 0) {
        float t = 0.0f;
        #pragma unroll
        for (int i = 0; i < 4; ++i) t += s[i];
        return t;
    }
    return 0.0f;
}

// ---------------------------------------------------------------------------
// Single kernel. Block roles:
//   [0,2048)    : streaming softplus sum over flattened det space
//   [2048,2063) : sparse correction, delta = -y*x - 0.5*y*softplus(-x)
// ---------------------------------------------------------------------------
__global__ void __launch_bounds__(256, 8) fused_main_kernel(
    const float* __restrict__ d0f, const float* __restrict__ d1f,
    const float* __restrict__ d2f, const float* __restrict__ anchors,
    const float* __restrict__ targets, float* __restrict__ partials) {
    float acc = 0.0f;

    if (blockIdx.x < NB_SCAN) {
        int g0 = blockIdx.x * 256 + threadIdx.x;
        int p0 = g0 % 5;
        // Depth-10 batch (k=0..9), then depth-5 batch (k=10..14): up to
        // 10 KB in flight per wave before the first waitcnt. Tensor select
        // is a block-uniform branchless pointer select.
        #define LOADJ(K, DEST)                                               \
        {                                                                    \
            const int idx = g0 + (K) * NT;                                   \
            const unsigned chunk = blockIdx.x + (unsigned)(K) * 2048u;       \
            const float* bp = (chunk < CH_B1) ? d0f                          \
                            : (chunk < CH_B2) ? d1f : d2f;                   \
            const int off = (chunk < CH_B1) ? idx                            \
                          : (chunk < CH_B2) ? (idx - OFF_D1)                 \
                                            : (idx - OFF_D2);                \
            DEST = __builtin_nontemporal_load((const float4n*)bp + off);     \
        }
        #define EATJ(K, SRC)                                                 \
        {                                                                    \
            const int c = (3 * (K)) % 5;                                     \
            int ph = p0 + c; if (ph >= 5) ph -= 5;                           \
            if (ph) acc += softplus_f(pickn(SRC, ph));                       \
        }
        {
            float4n f0, f1, f2, f3, f4, f5, f6, f7, f8, f9;
            LOADJ(0, f0) LOADJ(1, f1) LOADJ(2, f2) LOADJ(3, f3) LOADJ(4, f4)
            LOADJ(5, f5) LOADJ(6, f6) LOADJ(7, f7) LOADJ(8, f8) LOADJ(9, f9)
            EATJ(0, f0) EATJ(1, f1) EATJ(2, f2) EATJ(3, f3) EATJ(4, f4)
            EATJ(5, f5) EATJ(6, f6) EATJ(7, f7) EATJ(8, f8) EATJ(9, f9)
        }
        {
            float4n f0, f1, f2, f3, f4;
            LOADJ(10, f0) LOADJ(11, f1) LOADJ(12, f2) LOADJ(13, f3) LOADJ(14, f4)
            EATJ(10, f0) EATJ(11, f1) EATJ(12, f2) EATJ(13, f3) EATJ(14, f4)
        }
        #undef LOADJ
        #undef EATJ
        if (blockIdx.x < NB_16TH) {    // uniform 16th load, always det2
            int idx = g0 + 15 * NT;
            float4n f = __builtin_nontemporal_load(
                (const float4n*)d2f + (idx - OFF_D2));
            if (p0) acc += softplus_f(pickn(f, p0)); // phase = (p0+45)%5 = p0
        }
    } else {
        int t = (blockIdx.x - NB_SCAN) * 256 + threadIdx.x;
        if (t < BT) {
            int bi = t / T;
            const float* tg = targets + t * 4;
            float tx = tg[0], ty = tg[1], tw = tg[2], th = tg[3];
            bool mask = (tx != -1.0f) && (ty != -1.0f) &&
                        (tw != -1.0f) && (th != -1.0f);
            const int dims[NS] = {160, 80, 40};
            const float* dets[NS] = {d0f, d1f, d2f};

            float ov[NS][NA];
            float mx = -INFINITY;
            #pragma unroll
            for (int si = 0; si < NS; ++si) {
                float D = (float)dims[si];     // H == W at every scale
                float ztx = tx * D, zty = ty * D, ztw = tw * D, zth = th * D;
                float fx = ztx - (floorf(ztx) + 0.5f);
                float fy = zty - (floorf(zty) + 0.5f);
                float tarea = (ztw - fx) * (zth - fy);  // reference's exact expr
                #pragma unroll
                for (int ai = 0; ai < NA; ++ai) {
                    float a0 = anchors[(si * NA + ai) * 2 + 0];
                    float a1 = anchors[(si * NA + ai) * 2 + 1];
                    float lb0 = fmaxf(-0.5f * a0, fx - 0.5f * ztw);
                    float ub0 = fminf( 0.5f * a0, fx + 0.5f * ztw);
                    float lb1 = fmaxf(-0.5f * a1, fy - 0.5f * zth);
                    float ub1 = fminf( 0.5f * a1, fy + 0.5f * zth);
                    float m = ((lb0 < ub0) && (lb1 < ub1)) ? 1.0f : 0.0f;
                    float inter = (ub0 - lb0) * (ub1 - lb1) * m;
                    float v = inter / (a0 * a1 + tarea - inter);
                    ov[si][ai] = v;
                    mx = fmaxf(mx, v);
                }
            }
            if (mask) {
                #pragma unroll
                for (int si = 0; si < NS; ++si) {
                    int D = dims[si];
                    int cy = (int)(ty * (float)D);
                    int cx = (int)(tx * (float)D);
                    if (cy >= 0 && cy < D && cx >= 0 && cx < D) {
                        #pragma unroll
                        for (int ai = 0; ai < NA; ++ai) {
                            float v = ov[si][ai];
                            float y = (v == mx) ? 1.0f
                                    : ((v < 0.5f) ? 0.0f : -1.0f);
                            if (y != 0.0f) {
                                long idx = ((((long)bi * NA + ai) * D + cy) * D + cx) * 5 + 4;
                                float x = dets[si][idx];
                                acc += -y * x - 0.5f * y * softplus_f(-x);
                            }
                        }
                    }
                }
            }
        }
    }

    float bs = block_reduce_sum(acc);
    if (threadIdx.x == 0) partials[blockIdx.x] = bs;
}

// ---------------------------------------------------------------------------
// Final deterministic reduce of all 2063 block partials -> mean.
// ---------------------------------------------------------------------------
__global__ void __launch_bounds__(256) final_kernel(
    const float* __restrict__ wsf, float* __restrict__ out) {
    float acc = 0.0f;
    for (int i = threadIdx.x; i < NB_ALL; i += blockDim.x)
        acc += wsf[i];
    float bs = block_reduce_sum(acc);
    if (threadIdx.x == 0) out[0] = bs / N_TOTAL;
}

extern "C" void kernel_launch(void* const* d_in, const int* in_sizes, int n_in,
                              void* d_out, int out_size, void* d_ws, size_t ws_size,
                              hipStream_t stream) {
    const float* det0    = (const float*)d_in[0];
    const float* det1    = (const float*)d_in[1];
    const float* det2    = (const float*)d_in[2];
    const float* anchors = (const float*)d_in[3];
    const float* targets = (const float*)d_in[4];
    float* out = (float*)d_out;
    float* wsf = (float*)d_ws;

    fused_main_kernel<<<NB_ALL, 256, 0, stream>>>(det0, det1, det2,
                                                  anchors, targets, wsf);
    final_kernel<<<1, 256, 0, stream>>>(wsf, out);
}

// Round 14
// 27.860 us; speedup vs baseline: 1.1542x; 1.1542x over previous
//
#include <hip/hip_runtime.h>
#include <math.h>

// Problem constants (fixed by setup_inputs)
#define B 64
#define T 60
#define NA 3
#define NS 3
#define BT (B*T)

#define NB_SCAN 2048
#define NB_CORR ((BT + 255) / 256)    // 15
#define NB_ALL (NB_SCAN + NB_CORR)    // 2063 (corr blocks MUST be last: they
                                      // are the 15 non-resident overflow blocks)
#define NT 524288                     // scan threads; NT % 5 == 3
#define N_TOTAL 6451200.0f

// Flattened det space: 8064000 float4s. Chunk = 256 float4s.
// Tensor boundaries at chunk 24000 (det0/det1) and 30000 (det1/det2) are
// block-uniform because chunk(b,k) = b + 2048*k.
#define CH_B1 24000u
#define CH_B2 30000u
#define OFF_D1 6144000
#define OFF_D2 7680000
#define NB_16TH 780                   // blocks doing the 16th load (all det2)

typedef float float4n __attribute__((ext_vector_type(4)));

__device__ __forceinline__ float softplus_f(float x) {
    // stable softplus with fast hw transcendentals; abs err < 1e-6
    float e = __expf(-fabsf(x));
    return fmaxf(x, 0.0f) + __logf(1.0f + e);
}

__device__ __forceinline__ float pickn(float4n f, int ph) {
    // ph in 1..4 -> component ph-1 (caller gates ph==0)
    return (ph == 1) ? f[0] : (ph == 2) ? f[1] : (ph == 3) ? f[2] : f[3];
}

__device__ __forceinline__ float block_reduce_sum(float v) {
    __syncthreads();
    for (int o = 32; o > 0; o >>= 1) v += __shfl_down(v, o, 64);
    __shared__ float s[4];
    int lane = threadIdx.x & 63;
    int w = threadIdx.x >> 6;
    if (lane == 0) s[w] = v;
    __syncthreads();
    if (threadIdx.x == 0) {
        float t = 0.0f;
        #pragma unroll
        for (int i = 0; i < 4; ++i) t += s[i];
        return t;
    }
    return 0.0f;
}

// ---------------------------------------------------------------------------
// Single kernel. Block roles:
//   [0,2048)    : streaming softplus sum over flattened det space
//   [2048,2063) : sparse correction, delta = -y*x - 0.5*y*softplus(-x)
// ---------------------------------------------------------------------------
__global__ void __launch_bounds__(256, 8) fused_main_kernel(
    const float* __restrict__ d0f, const float* __restrict__ d1f,
    const float* __restrict__ d2f, const float* __restrict__ anchors,
    const float* __restrict__ targets, float* __restrict__ partials) {
    float acc = 0.0f;

    if (blockIdx.x < NB_SCAN) {
        int g0 = blockIdx.x * 256 + threadIdx.x;
        int p0 = g0 % 5;
        // 3 groups of 5 batched NT loads; tensor select is a block-uniform
        // branchless pointer select (no control flow between loads).
        #pragma unroll
        for (int grp = 0; grp < 3; ++grp) {
            float4n f0, f1, f2, f3, f4;
            #define LOADJ(J, DEST)                                           \
            {                                                                \
                const int k = grp * 5 + (J);                                 \
                const int idx = g0 + k * NT;                                 \
                const unsigned chunk = blockIdx.x + (unsigned)k * 2048u;     \
                const float* bp = (chunk < CH_B1) ? d0f                      \
                                : (chunk < CH_B2) ? d1f : d2f;               \
                const int off = (chunk < CH_B1) ? idx                        \
                              : (chunk < CH_B2) ? (idx - OFF_D1)             \
                                                : (idx - OFF_D2);            \
                DEST = __builtin_nontemporal_load((const float4n*)bp + off); \
            }
            LOADJ(0, f0) LOADJ(1, f1) LOADJ(2, f2) LOADJ(3, f3) LOADJ(4, f4)
            #undef LOADJ
            // phase for load k: (p0 + 3k) mod 5 — every thread hits phase 0
            // exactly once per group of 5.
            #define EATJ(J, SRC)                                             \
            {                                                                \
                const int c = (3 * (grp * 5 + (J))) % 5;                     \
                int ph = p0 + c; if (ph >= 5) ph -= 5;                       \
                if (ph) acc += softplus_f(pickn(SRC, ph));                   \
            }
            EATJ(0, f0) EATJ(1, f1) EATJ(2, f2) EATJ(3, f3) EATJ(4, f4)
            #undef EATJ
        }
        if (blockIdx.x < NB_16TH) {    // uniform 16th load, always det2
            int idx = g0 + 15 * NT;
            float4n f = __builtin_nontemporal_load(
                (const float4n*)d2f + (idx - OFF_D2));
            if (p0) acc += softplus_f(pickn(f, p0)); // phase = (p0+45)%5 = p0
        }
    } else {
        int t = (blockIdx.x - NB_SCAN) * 256 + threadIdx.x;
        if (t < BT) {
            int bi = t / T;
            const float* tg = targets + t * 4;
            float tx = tg[0], ty = tg[1], tw = tg[2], th = tg[3];
            bool mask = (tx != -1.0f) && (ty != -1.0f) &&
                        (tw != -1.0f) && (th != -1.0f);
            const int dims[NS] = {160, 80, 40};
            const float* dets[NS] = {d0f, d1f, d2f};

            float ov[NS][NA];
            float mx = -INFINITY;
            #pragma unroll
            for (int si = 0; si < NS; ++si) {
                float D = (float)dims[si];     // H == W at every scale
                float ztx = tx * D, zty = ty * D, ztw = tw * D, zth = th * D;
                float fx = ztx - (floorf(ztx) + 0.5f);
                float fy = zty - (floorf(zty) + 0.5f);
                float tarea = (ztw - fx) * (zth - fy);  // reference's exact expr
                #pragma unroll
                for (int ai = 0; ai < NA; ++ai) {
                    float a0 = anchors[(si * NA + ai) * 2 + 0];
                    float a1 = anchors[(si * NA + ai) * 2 + 1];
                    float lb0 = fmaxf(-0.5f * a0, fx - 0.5f * ztw);
                    float ub0 = fminf( 0.5f * a0, fx + 0.5f * ztw);
                    float lb1 = fmaxf(-0.5f * a1, fy - 0.5f * zth);
                    float ub1 = fminf( 0.5f * a1, fy + 0.5f * zth);
                    float m = ((lb0 < ub0) && (lb1 < ub1)) ? 1.0f : 0.0f;
                    float inter = (ub0 - lb0) * (ub1 - lb1) * m;
                    float v = inter / (a0 * a1 + tarea - inter);
                    ov[si][ai] = v;
                    mx = fmaxf(mx, v);
                }
            }
            if (mask) {
                #pragma unroll
                for (int si = 0; si < NS; ++si) {
                    int D = dims[si];
                    int cy = (int)(ty * (float)D);
                    int cx = (int)(tx * (float)D);
                    if (cy >= 0 && cy < D && cx >= 0 && cx < D) {
                        #pragma unroll
                        for (int ai = 0; ai < NA; ++ai) {
                            float v = ov[si][ai];
                            float y = (v == mx) ? 1.0f
                                    : ((v < 0.5f) ? 0.0f : -1.0f);
                            if (y != 0.0f) {
                                long idx = ((((long)bi * NA + ai) * D + cy) * D + cx) * 5 + 4;
                                float x = dets[si][idx];
                                acc += -y * x - 0.5f * y * softplus_f(-x);
                            }
                        }
                    }
                }
            }
        }
    }

    float bs = block_reduce_sum(acc);
    if (threadIdx.x == 0) partials[blockIdx.x] = bs;
}

// ---------------------------------------------------------------------------
// Final deterministic reduce of all 2063 block partials -> mean.
// ---------------------------------------------------------------------------
__global__ void __launch_bounds__(256) final_kernel(
    const float* __restrict__ wsf, float* __restrict__ out) {
    float acc = 0.0f;
    for (int i = threadIdx.x; i < NB_ALL; i += blockDim.x)
        acc += wsf[i];
    float bs = block_reduce_sum(acc);
    if (threadIdx.x == 0) out[0] = bs / N_TOTAL;
}

extern "C" void kernel_launch(void* const* d_in, const int* in_sizes, int n_in,
                              void* d_out, int out_size, void* d_ws, size_t ws_size,
                              hipStream_t stream) {
    const float* det0    = (const float*)d_in[0];
    const float* det1    = (const float*)d_in[1];
    const float* det2    = (const float*)d_in[2];
    const float* anchors = (const float*)d_in[3];
    const float* targets = (const float*)d_in[4];
    float* out = (float*)d_out;
    float* wsf = (float*)d_ws;

    fused_main_kernel<<<NB_ALL, 256, 0, stream>>>(det0, det1, det2,
                                                  anchors, targets, wsf);
    final_kernel<<<1, 256, 0, stream>>>(wsf, out);
}